// Round 5
// baseline (197.893 us; speedup 1.0000x reference)
//
#include <hip/hip_runtime.h>
#include <stdint.h>
#include <stddef.h>

typedef __attribute__((ext_vector_type(8))) short short8;
typedef __attribute__((ext_vector_type(4))) float f32x4;
typedef __attribute__((ext_vector_type(16))) float f32x16;
typedef __attribute__((ext_vector_type(4))) unsigned short ushort4v;
typedef __attribute__((ext_vector_type(4))) unsigned int uint4v;

#define SEQ   2048
#define NH    16
#define BATCH 4
#define GK    1024

__device__ __forceinline__ unsigned short f2bf(float f) {
  union { float f; unsigned int u; } v; v.f = f;
  unsigned int u = v.u;
  u += 0x7fffu + ((u >> 16) & 1u);
  return (unsigned short)(u >> 16);
}

__device__ __forceinline__ unsigned cvtpk_bf16(float lo, float hi) {
  unsigned r;
  asm("v_cvt_pk_bf16_f32 %0, %1, %2" : "=v"(r) : "v"(lo), "v"(hi));
  return r;
}

// swap halves: x' = {x.lanes0-31, y.lanes0-31}; y' = {x.lanes32-63, y.lanes32-63}
__device__ __forceinline__ void plswap(unsigned &x, unsigned &y) {
#if __has_builtin(__builtin_amdgcn_permlane32_swap)
  auto r = __builtin_amdgcn_permlane32_swap((int)x, (int)y, false, false);
  x = (unsigned)r[0]; y = (unsigned)r[1];
#else
  const unsigned sx = (unsigned)__shfl_xor((int)x, 32);
  const unsigned sy = (unsigned)__shfl_xor((int)y, 32);
  const bool hi = (threadIdx.x & 63) >= 32;
  const unsigned nx = hi ? sy : x;
  const unsigned ny = hi ? y : sx;
  x = nx; y = ny;
#endif
}

__device__ __forceinline__ void gload16(const unsigned short* g, unsigned short* l) {
  __builtin_amdgcn_global_load_lds(
      (const __attribute__((address_space(1))) unsigned int*)g,
      (__attribute__((address_space(3))) unsigned int*)l, 16, 0, 0);
}

// ---------------- fp32 -> bf16 convert ----------------
__global__ void cvt_bf16(const float* __restrict__ src, unsigned short* __restrict__ dst, int n4) {
  int i = blockIdx.x * blockDim.x + threadIdx.x;
  const int stride = gridDim.x * blockDim.x;
  for (; i < n4; i += stride) {
    const float4 v = reinterpret_cast<const float4*>(src)[i];
    ushort4v o;
    o[0] = f2bf(v.x); o[1] = f2bf(v.y); o[2] = f2bf(v.z); o[3] = f2bf(v.w);
    reinterpret_cast<ushort4v*>(dst)[i] = o;
  }
}

// ---------------- GEMM: C[m,n] = sum_k A[m,k]*Bw[n,k] + bias[n] ----------------
template<int MODE>
__global__ __launch_bounds__(256, 3)
void gemm_bt(const unsigned short* __restrict__ A,
             const unsigned short* __restrict__ Bw,
             const float* __restrict__ bias,
             unsigned short* __restrict__ q_ws,
             unsigned short* __restrict__ k_ws,
             unsigned short* __restrict__ v_ws,
             float* __restrict__ fout,
             int N)
{
  __shared__ __attribute__((aligned(16))) unsigned short As[128 * 64];
  __shared__ __attribute__((aligned(16))) unsigned short Bs[128 * 64];

  const int t = threadIdx.x;
  const int w = t >> 6, lane = t & 63;
  const int g = lane >> 4, c = lane & 15;
  const int wrow = w >> 1, wcol = w & 1;
  const int m0 = blockIdx.y * 128;
  const int n0 = blockIdx.x * 128;

  const int r8 = lane >> 3;
  const int cgs = (lane & 7) ^ r8;

  const f32x4 fz = {0.f, 0.f, 0.f, 0.f};
  f32x4 acc[4][4];
#pragma unroll
  for (int i = 0; i < 4; ++i)
#pragma unroll
    for (int j = 0; j < 4; ++j) acc[i][j] = fz;

  for (int ks = 0; ks < GK; ks += 64) {
    __syncthreads();
#pragma unroll
    for (int i = 0; i < 4; ++i) {
      const int RB = (i * 4 + w) * 8;
      gload16(A + (size_t)(m0 + RB + r8) * GK + ks + cgs * 8, &As[RB * 64]);
      gload16(Bw + (size_t)(n0 + RB + r8) * GK + ks + cgs * 8, &Bs[RB * 64]);
    }
    __syncthreads();
#pragma unroll
    for (int kk = 0; kk < 2; ++kk) {
      short8 af[4], bfr[4];
#pragma unroll
      for (int mi = 0; mi < 4; ++mi) {
        const int row = wrow * 64 + mi * 16 + c;
        af[mi] = *reinterpret_cast<const short8*>(&As[row * 64 + (((kk * 4 + g) ^ (row & 7)) << 3)]);
      }
#pragma unroll
      for (int ni = 0; ni < 4; ++ni) {
        const int row = wcol * 64 + ni * 16 + c;
        bfr[ni] = *reinterpret_cast<const short8*>(&Bs[row * 64 + (((kk * 4 + g) ^ (row & 7)) << 3)]);
      }
#pragma unroll
      for (int mi = 0; mi < 4; ++mi)
#pragma unroll
        for (int ni = 0; ni < 4; ++ni)
          acc[mi][ni] = __builtin_amdgcn_mfma_f32_16x16x32_bf16(af[mi], bfr[ni], acc[mi][ni], 0, 0, 0);
    }
  }

  if (MODE == 0) {
    const int sec = n0 >> 10;  // 0=q 1=k 2=v
    unsigned short* dst = (sec == 0) ? q_ws : ((sec == 1) ? k_ws : v_ws);
    const float qsc = (sec == 0) ? (0.125f * 1.44269504f) : 1.0f;
#pragma unroll
    for (int ni = 0; ni < 4; ++ni) {
      const int n = n0 + wcol * 64 + ni * 16 + c;
      const float bb = bias[n];
      const int hh = (n & 1023) >> 6;
      const int d = n & 63;
#pragma unroll
      for (int mi = 0; mi < 4; ++mi) {
#pragma unroll
        for (int r = 0; r < 4; ++r) {
          const int m = m0 + wrow * 64 + mi * 16 + g * 4 + r;
          const int b = m >> 11, s = m & 2047;
          const float val = (acc[mi][ni][r] + bb) * qsc;
          dst[((size_t)((b * NH + hh) * SEQ + s) << 6) + d] = f2bf(val);
        }
      }
    }
  } else {
#pragma unroll
    for (int ni = 0; ni < 4; ++ni) {
      const int n = n0 + wcol * 64 + ni * 16 + c;
      const float bb = bias[n];
#pragma unroll
      for (int mi = 0; mi < 4; ++mi) {
#pragma unroll
        for (int r = 0; r < 4; ++r) {
          const int m = m0 + wrow * 64 + mi * 16 + g * 4 + r;
          fout[(size_t)m * N + n] = acc[mi][ni][r] + bb;
        }
      }
    }
  }
}

// ---------------- V transpose: [bh][s][64] -> [bh][d][SEQ] ----------------
__global__ __launch_bounds__(256)
void transpose_v(const unsigned short* __restrict__ v, unsigned short* __restrict__ vt) {
  __shared__ unsigned short T[64][72];
  const int t = threadIdx.x;
  const int bh = blockIdx.y, s0 = blockIdx.x * 64;
  const unsigned short* src = v + ((size_t)bh * SEQ + s0) * 64;
#pragma unroll
  for (int rep = 0; rep < 2; ++rep) {
    const int u = rep * 256 + t;
    const int sr = u >> 3, cg = u & 7;
    const short8 x = *reinterpret_cast<const short8*>(src + (size_t)sr * 64 + cg * 8);
    *reinterpret_cast<short8*>(&T[sr][cg * 8]) = x;
  }
  __syncthreads();
  unsigned short* dst = vt + (size_t)bh * 64 * SEQ + s0;
#pragma unroll
  for (int rep = 0; rep < 2; ++rep) {
    const int u = rep * 256 + t;
    const int d = u >> 3, sc8 = u & 7;
    short8 x;
#pragma unroll
    for (int j = 0; j < 8; ++j) x[j] = (short)T[sc8 * 8 + j][d];
    *reinterpret_cast<short8*>(dst + (size_t)d * SEQ + sc8 * 8) = x;
  }
}

// ---------------- flash attention (causal), 4-wave blocks, 4 blocks/CU ----------------
// grid (16, 64): block = 128-row q-tile jt (balanced map), 4 waves x 32 q-rows.
// K/V^T double-buffered swizzled LDS (32KB); swapped QK^T; register-P softmax
// (cvt_pk + permlane32_swap); defer-max; exp2-domain (log2e folded into q).
__global__ __launch_bounds__(256, 4)
void attn_fwd5(const unsigned short* __restrict__ q_ws,
               const unsigned short* __restrict__ k_ws,
               const unsigned short* __restrict__ vt_ws,
               unsigned short* __restrict__ y_ws)
{
  __shared__ __attribute__((aligned(16))) unsigned short Ks[2][64 * 64];
  __shared__ __attribute__((aligned(16))) unsigned short Vs[2][64 * 64];

  const int t = threadIdx.x;
  const int w = t >> 6, lane = t & 63;
  const int ql = lane & 31, hi = lane >> 5;
  const int bh = blockIdx.y, b = bh >> 4, h = bh & 15;
  // balanced tile map: pairs (j, 15-j) across the by-halves -> equal per-CU work
  const int jt = (blockIdx.y >= 32) ? (15 - (int)blockIdx.x) : (int)blockIdx.x;
  const int wq0 = jt * 128 + w * 32;
  const int nkt = 2 * jt + 2;

  const int s_row = t >> 3, s_cg = t & 7;   // 256 threads cover 32 rows x 8 chunks per rep
  const int so0 = s_row * 64 + ((s_cg ^ (s_row & 7)) << 3);
  const int so1 = (s_row + 32) * 64 + ((s_cg ^ (s_row & 7)) << 3);

  const unsigned short* kbase = k_ws + (size_t)bh * SEQ * 64;
  const unsigned short* vbase = vt_ws + (size_t)bh * 64 * SEQ;

  short8 rk0, rk1, rv0, rv1;
  auto stage_issue = [&](int kt) {
    const unsigned short* kp = kbase + (size_t)kt * 4096;
    rk0 = *reinterpret_cast<const short8*>(kp + (size_t)s_row * 64 + s_cg * 8);
    rk1 = *reinterpret_cast<const short8*>(kp + (size_t)(s_row + 32) * 64 + s_cg * 8);
    const unsigned short* vp = vbase + (size_t)kt * 64;
    rv0 = *reinterpret_cast<const short8*>(vp + (size_t)s_row * SEQ + s_cg * 8);
    rv1 = *reinterpret_cast<const short8*>(vp + (size_t)(s_row + 32) * SEQ + s_cg * 8);
  };
  auto stage_write = [&](int bi) {
    *reinterpret_cast<short8*>(&Ks[bi][so0]) = rk0;
    *reinterpret_cast<short8*>(&Ks[bi][so1]) = rk1;
    *reinterpret_cast<short8*>(&Vs[bi][so0]) = rv0;
    *reinterpret_cast<short8*>(&Vs[bi][so1]) = rv1;
  };

  // Q fragments: lane holds Q[q = wq0+ql][d = 16*ks + 8*hi + j]
  const unsigned short* qr = q_ws + ((size_t)bh * SEQ + (wq0 + ql)) * 64;
  short8 qf[4];
#pragma unroll
  for (int ks = 0; ks < 4; ++ks)
    qf[ks] = *reinterpret_cast<const short8*>(qr + ks * 16 + hi * 8);

  f32x16 o0, o1;
#pragma unroll
  for (int i = 0; i < 16; ++i) { o0[i] = 0.f; o1[i] = 0.f; }
  float m_run = -1e30f, lsum = 0.f;

  stage_issue(0);
  stage_write(0);

#pragma unroll 1
  for (int kt = 0; kt < nkt; ++kt) {
    const bool more = (kt + 1) < nkt;
    if (more) stage_issue(kt + 1);     // issue-early (T14)
    __syncthreads();
    const int cur = kt & 1;
    const int kt64 = kt * 64;

    if (kt64 <= wq0 + 31) {            // wave-uniform activity gate
      // K fragments
      short8 kfl[4], kfh[4];
#pragma unroll
      for (int ks = 0; ks < 4; ++ks) {
        kfl[ks] = *reinterpret_cast<const short8*>(
            &Ks[cur][ql * 64 + (((2 * ks + hi) ^ (ql & 7)) << 3)]);
        kfh[ks] = *reinterpret_cast<const short8*>(
            &Ks[cur][(32 + ql) * 64 + (((2 * ks + hi) ^ (ql & 7)) << 3)]);
      }
      // ---- QK^T (swapped: D[key][q], col=lane&31=q) ----
      f32x16 s0, s1;
#pragma unroll
      for (int i = 0; i < 16; ++i) { s0[i] = 0.f; s1[i] = 0.f; }
      __builtin_amdgcn_s_setprio(1);
#pragma unroll
      for (int ks = 0; ks < 4; ++ks) {
        s0 = __builtin_amdgcn_mfma_f32_32x32x16_bf16(kfl[ks], qf[ks], s0, 0, 0, 0);
        s1 = __builtin_amdgcn_mfma_f32_32x32x16_bf16(kfh[ks], qf[ks], s1, 0, 0, 0);
      }
      __builtin_amdgcn_s_setprio(0);
      // ---- causal mask (diagonal straddle only) ----
      if (kt64 + 63 > wq0) {
        const int gq = wq0 + ql;
#pragma unroll
        for (int r = 0; r < 16; ++r) {
          const int krow = (r & 3) + 8 * (r >> 2) + 4 * hi;
          if (kt64 + krow > gq)      s0[r] = -1e30f;
          if (kt64 + 32 + krow > gq) s1[r] = -1e30f;
        }
      }
      // ---- online softmax (log2 domain), defer-max THR=10 ----
      float tm = -1e30f;
#pragma unroll
      for (int r = 0; r < 16; ++r) tm = fmaxf(tm, fmaxf(s0[r], s1[r]));
      tm = fmaxf(tm, __shfl_xor(tm, 32));
      if (__any(tm > m_run + 10.0f)) {
        const float m_new = fmaxf(m_run, tm);
        const float al = __builtin_amdgcn_exp2f(m_run - m_new);
        m_run = m_new;
        lsum *= al;
#pragma unroll
        for (int r = 0; r < 16; ++r) {
          const int qq = (r & 3) + 8 * (r >> 2) + 4 * hi;
          const float ar = __shfl(al, qq);
          o0[r] *= ar; o1[r] *= ar;
        }
      }
      float psum = 0.f;
      unsigned W[16];
#pragma unroll
      for (int half = 0; half < 2; ++half) {
#pragma unroll
        for (int gr = 0; gr < 4; ++gr) {
          const float v0 = (half ? s1[gr * 4 + 0] : s0[gr * 4 + 0]) - m_run;
          const float v1 = (half ? s1[gr * 4 + 1] : s0[gr * 4 + 1]) - m_run;
          const float v2 = (half ? s1[gr * 4 + 2] : s0[gr * 4 + 2]) - m_run;
          const float v3 = (half ? s1[gr * 4 + 3] : s0[gr * 4 + 3]) - m_run;
          const float p0 = __builtin_amdgcn_exp2f(v0);
          const float p1 = __builtin_amdgcn_exp2f(v1);
          const float p2 = __builtin_amdgcn_exp2f(v2);
          const float p3 = __builtin_amdgcn_exp2f(v3);
          psum += (p0 + p1) + (p2 + p3);
          W[half * 8 + 2 * gr]     = cvtpk_bf16(p0, p1);
          W[half * 8 + 2 * gr + 1] = cvtpk_bf16(p2, p3);
        }
      }
      lsum += psum;
      // redistribute P into PV A-operand fragments (register-only)
      short8 pa[4];
#pragma unroll
      for (int q4 = 0; q4 < 4; ++q4) {
        unsigned a0 = W[q4 * 4 + 0], a1 = W[q4 * 4 + 2];
        unsigned b0 = W[q4 * 4 + 1], b1 = W[q4 * 4 + 3];
        plswap(a0, a1);
        plswap(b0, b1);
        uint4v pk; pk[0] = a0; pk[1] = b0; pk[2] = a1; pk[3] = b1;
        pa[q4] = __builtin_bit_cast(short8, pk);
      }
      // ---- PV ----
      __builtin_amdgcn_s_setprio(1);
#pragma unroll
      for (int ks = 0; ks < 4; ++ks) {
        const short8 vfl = *reinterpret_cast<const short8*>(
            &Vs[cur][ql * 64 + (((2 * ks + hi) ^ (ql & 7)) << 3)]);
        const short8 vfh = *reinterpret_cast<const short8*>(
            &Vs[cur][(32 + ql) * 64 + (((2 * ks + hi) ^ (ql & 7)) << 3)]);
        o0 = __builtin_amdgcn_mfma_f32_32x32x16_bf16(pa[ks], vfl, o0, 0, 0, 0);
        o1 = __builtin_amdgcn_mfma_f32_32x32x16_bf16(pa[ks], vfh, o1, 0, 0, 0);
      }
      __builtin_amdgcn_s_setprio(0);
    }
    if (more) stage_write((kt + 1) & 1);   // write-late (T14)
  }

  // ---- epilogue ----
  lsum += __shfl_xor(lsum, 32);
  const float linv = 1.f / lsum;
#pragma unroll
  for (int r = 0; r < 16; ++r) {
    const int qq = (r & 3) + 8 * (r >> 2) + 4 * hi;
    const float lr = __shfl(linv, qq);
    const size_t rowo = ((size_t)b * SEQ + (wq0 + qq)) * 1024 + h * 64;
    y_ws[rowo + ql]      = f2bf(o0[r] * lr);
    y_ws[rowo + 32 + ql] = f2bf(o1[r] * lr);
  }
}

extern "C" void kernel_launch(void* const* d_in, const int* in_sizes, int n_in,
                              void* d_out, int out_size, void* d_ws, size_t ws_size,
                              hipStream_t stream)
{
  (void)in_sizes; (void)n_in; (void)out_size; (void)ws_size;
  const float* x     = (const float*)d_in[0];
  const float* W_qkv = (const float*)d_in[1];
  const float* b_qkv = (const float*)d_in[2];
  const float* W_out = (const float*)d_in[3];
  const float* b_out = (const float*)d_in[4];
  float* out = (float*)d_out;

  unsigned short* ws      = (unsigned short*)d_ws;
  unsigned short* x_bf    = ws;
  unsigned short* wqkv_bf = x_bf    + (size_t)8192 * 1024;
  unsigned short* wout_bf = wqkv_bf + (size_t)3072 * 1024;
  unsigned short* q_ws    = wout_bf + (size_t)1024 * 1024;
  unsigned short* k_ws    = q_ws    + (size_t)64 * SEQ * 64;
  unsigned short* v_ws    = k_ws    + (size_t)64 * SEQ * 64;
  unsigned short* y_ws    = v_ws    + (size_t)64 * SEQ * 64;
  unsigned short* vt_ws   = x_bf;   // x_bf dead after qkv GEMM

  cvt_bf16<<<2048, 256, 0, stream>>>(x,     x_bf,    (8192 * 1024) / 4);
  cvt_bf16<<<1024, 256, 0, stream>>>(W_qkv, wqkv_bf, (3072 * 1024) / 4);
  cvt_bf16<<<512,  256, 0, stream>>>(W_out, wout_bf, (1024 * 1024) / 4);

  gemm_bt<0><<<dim3(24, 64), 256, 0, stream>>>(x_bf, wqkv_bf, b_qkv, q_ws, k_ws, v_ws, nullptr, 3072);
  transpose_v<<<dim3(SEQ / 64, 64), 256, 0, stream>>>(v_ws, vt_ws);
  attn_fwd5<<<dim3(16, 64), 256, 0, stream>>>(q_ws, k_ws, vt_ws, y_ws);
  gemm_bt<1><<<dim3(8, 64), 256, 0, stream>>>(y_ws, wout_bf, b_out, nullptr, nullptr, nullptr, out, 1024);
}

// Round 6
// 183.327 us; speedup vs baseline: 1.0795x; 1.0795x over previous
//
#include <hip/hip_runtime.h>
#include <stdint.h>
#include <stddef.h>

typedef __attribute__((ext_vector_type(8))) short short8;
typedef __attribute__((ext_vector_type(4))) float f32x4;
typedef __attribute__((ext_vector_type(16))) float f32x16;
typedef __attribute__((ext_vector_type(4))) unsigned short ushort4v;
typedef __attribute__((ext_vector_type(4))) unsigned int uint4v;

#define SEQ   2048
#define NH    16
#define BATCH 4
#define GK    1024

__device__ __forceinline__ unsigned short f2bf(float f) {
  union { float f; unsigned int u; } v; v.f = f;
  unsigned int u = v.u;
  u += 0x7fffu + ((u >> 16) & 1u);
  return (unsigned short)(u >> 16);
}

__device__ __forceinline__ unsigned cvtpk_bf16(float lo, float hi) {
  unsigned r;
  asm("v_cvt_pk_bf16_f32 %0, %1, %2" : "=v"(r) : "v"(lo), "v"(hi));
  return r;
}

// swap halves: x' = {x.lanes0-31, y.lanes0-31}; y' = {x.lanes32-63, y.lanes32-63}
__device__ __forceinline__ void plswap(unsigned &x, unsigned &y) {
#if __has_builtin(__builtin_amdgcn_permlane32_swap)
  auto r = __builtin_amdgcn_permlane32_swap((int)x, (int)y, false, false);
  x = (unsigned)r[0]; y = (unsigned)r[1];
#else
  const unsigned sx = (unsigned)__shfl_xor((int)x, 32);
  const unsigned sy = (unsigned)__shfl_xor((int)y, 32);
  const bool hi = (threadIdx.x & 63) >= 32;
  const unsigned nx = hi ? sy : x;
  const unsigned ny = hi ? y : sx;
  x = nx; y = ny;
#endif
}

__device__ __forceinline__ void gload16(const unsigned short* g, unsigned short* l) {
  __builtin_amdgcn_global_load_lds(
      (const __attribute__((address_space(1))) unsigned int*)g,
      (__attribute__((address_space(3))) unsigned int*)l, 16, 0, 0);
}

// ---------------- fp32 -> bf16 convert (all three inputs, one kernel) ----------------
__global__ void cvt_all(const float* __restrict__ x, const float* __restrict__ wqkv,
                        const float* __restrict__ wout, unsigned short* __restrict__ dst) {
  const int N1 = (8192 * 1024) / 4, N2 = (3072 * 1024) / 4, N3 = (1024 * 1024) / 4;
  int i = blockIdx.x * blockDim.x + threadIdx.x;
  const int stride = gridDim.x * blockDim.x;
  for (; i < N1 + N2 + N3; i += stride) {
    float4 v;
    if (i < N1)            v = reinterpret_cast<const float4*>(x)[i];
    else if (i < N1 + N2)  v = reinterpret_cast<const float4*>(wqkv)[i - N1];
    else                   v = reinterpret_cast<const float4*>(wout)[i - N1 - N2];
    ushort4v o;
    o[0] = f2bf(v.x); o[1] = f2bf(v.y); o[2] = f2bf(v.z); o[3] = f2bf(v.w);
    reinterpret_cast<ushort4v*>(dst)[i] = o;
  }
}

// ---------------- GEMM: C[m,n] = sum_k A[m,k]*Bw[n,k] + bias[n] ----------------
template<int MODE>
__global__ __launch_bounds__(256, 3)
void gemm_bt(const unsigned short* __restrict__ A,
             const unsigned short* __restrict__ Bw,
             const float* __restrict__ bias,
             unsigned short* __restrict__ q_ws,
             unsigned short* __restrict__ k_ws,
             unsigned short* __restrict__ v_ws,
             float* __restrict__ fout,
             int N)
{
  __shared__ __attribute__((aligned(16))) unsigned short As[128 * 64];
  __shared__ __attribute__((aligned(16))) unsigned short Bs[128 * 64];

  const int t = threadIdx.x;
  const int w = t >> 6, lane = t & 63;
  const int g = lane >> 4, c = lane & 15;
  const int wrow = w >> 1, wcol = w & 1;
  const int m0 = blockIdx.y * 128;
  const int n0 = blockIdx.x * 128;

  const int r8 = lane >> 3;
  const int cgs = (lane & 7) ^ r8;

  const f32x4 fz = {0.f, 0.f, 0.f, 0.f};
  f32x4 acc[4][4];
#pragma unroll
  for (int i = 0; i < 4; ++i)
#pragma unroll
    for (int j = 0; j < 4; ++j) acc[i][j] = fz;

  for (int ks = 0; ks < GK; ks += 64) {
    __syncthreads();
#pragma unroll
    for (int i = 0; i < 4; ++i) {
      const int RB = (i * 4 + w) * 8;
      gload16(A + (size_t)(m0 + RB + r8) * GK + ks + cgs * 8, &As[RB * 64]);
      gload16(Bw + (size_t)(n0 + RB + r8) * GK + ks + cgs * 8, &Bs[RB * 64]);
    }
    __syncthreads();
#pragma unroll
    for (int kk = 0; kk < 2; ++kk) {
      short8 af[4], bfr[4];
#pragma unroll
      for (int mi = 0; mi < 4; ++mi) {
        const int row = wrow * 64 + mi * 16 + c;
        af[mi] = *reinterpret_cast<const short8*>(&As[row * 64 + (((kk * 4 + g) ^ (row & 7)) << 3)]);
      }
#pragma unroll
      for (int ni = 0; ni < 4; ++ni) {
        const int row = wcol * 64 + ni * 16 + c;
        bfr[ni] = *reinterpret_cast<const short8*>(&Bs[row * 64 + (((kk * 4 + g) ^ (row & 7)) << 3)]);
      }
#pragma unroll
      for (int mi = 0; mi < 4; ++mi)
#pragma unroll
        for (int ni = 0; ni < 4; ++ni)
          acc[mi][ni] = __builtin_amdgcn_mfma_f32_16x16x32_bf16(af[mi], bfr[ni], acc[mi][ni], 0, 0, 0);
    }
  }

  if (MODE == 0) {
    const int sec = n0 >> 10;  // 0=q 1=k 2=v
    unsigned short* dst = (sec == 0) ? q_ws : ((sec == 1) ? k_ws : v_ws);
    const float qsc = (sec == 0) ? (0.125f * 1.44269504f) : 1.0f;
#pragma unroll
    for (int ni = 0; ni < 4; ++ni) {
      const int n = n0 + wcol * 64 + ni * 16 + c;
      const float bb = bias[n];
      const int hh = (n & 1023) >> 6;
      const int d = n & 63;
#pragma unroll
      for (int mi = 0; mi < 4; ++mi) {
#pragma unroll
        for (int r = 0; r < 4; ++r) {
          const int m = m0 + wrow * 64 + mi * 16 + g * 4 + r;
          const int b = m >> 11, s = m & 2047;
          const float val = (acc[mi][ni][r] + bb) * qsc;
          dst[((size_t)((b * NH + hh) * SEQ + s) << 6) + d] = f2bf(val);
        }
      }
    }
  } else {
#pragma unroll
    for (int ni = 0; ni < 4; ++ni) {
      const int n = n0 + wcol * 64 + ni * 16 + c;
      const float bb = bias[n];
#pragma unroll
      for (int mi = 0; mi < 4; ++mi) {
#pragma unroll
        for (int r = 0; r < 4; ++r) {
          const int m = m0 + wrow * 64 + mi * 16 + g * 4 + r;
          fout[(size_t)m * N + n] = acc[mi][ni][r] + bb;
        }
      }
    }
  }
}

// ---------------- V transpose: [bh][s][64] -> [bh][d][SEQ] ----------------
__global__ __launch_bounds__(256)
void transpose_v(const unsigned short* __restrict__ v, unsigned short* __restrict__ vt) {
  __shared__ unsigned short T[64][72];
  const int t = threadIdx.x;
  const int bh = blockIdx.y, s0 = blockIdx.x * 64;
  const unsigned short* src = v + ((size_t)bh * SEQ + s0) * 64;
#pragma unroll
  for (int rep = 0; rep < 2; ++rep) {
    const int u = rep * 256 + t;
    const int sr = u >> 3, cg = u & 7;
    const short8 x = *reinterpret_cast<const short8*>(src + (size_t)sr * 64 + cg * 8);
    *reinterpret_cast<short8*>(&T[sr][cg * 8]) = x;
  }
  __syncthreads();
  unsigned short* dst = vt + (size_t)bh * 64 * SEQ + s0;
#pragma unroll
  for (int rep = 0; rep < 2; ++rep) {
    const int u = rep * 256 + t;
    const int d = u >> 3, sc8 = u & 7;
    short8 x;
#pragma unroll
    for (int j = 0; j < 8; ++j) x[j] = (short)T[sc8 * 8 + j][d];
    *reinterpret_cast<short8*>(dst + (size_t)d * SEQ + sc8 * 8) = x;
  }
}

// ---------------- flash attention (causal), 8-wave blocks (R4 base) ----------------
// grid (8, 64): block = 256-row q-tile jt (balanced map), 8 waves x 32 q-rows.
// NEW vs R4: (1) K/V staged via global_load_lds (linear LDS dest, inverse-swizzled
// global source -> same swizzled LDS image); (2) T15 att[2]: per iter QK(t) ->
// PV(t-1) -> softmax(t), V triple-buffered so PV(t-1) never races V(t+1) staging.
__global__ __launch_bounds__(512, 4)
void attn_fwd6(const unsigned short* __restrict__ q_ws,
               const unsigned short* __restrict__ k_ws,
               const unsigned short* __restrict__ vt_ws,
               unsigned short* __restrict__ y_ws)
{
  __shared__ __attribute__((aligned(16))) unsigned short Ks[2][64 * 64];
  __shared__ __attribute__((aligned(16))) unsigned short Vs[3][64 * 64];

  const int t = threadIdx.x;
  const int w = t >> 6, lane = t & 63;
  const int ql = lane & 31, hi = lane >> 5;
  const int bh = blockIdx.y, b = bh >> 4, h = bh & 15;
  const int jt = (blockIdx.y >= 32) ? (7 - (int)blockIdx.x) : (int)blockIdx.x;
  const int wq0 = jt * 256 + w * 32;
  const int nkt = 4 * jt + 4;

  // staging: thread t owns LDS row s_row = t>>3 (64 rows), LDS chunk t&7.
  // gload_lds dest is linear (wave base + lane*16B); source chunk is inverse-swizzled
  // so LDS chunk p of row r holds global chunk p^(r&7)  (same image as R4).
  const int s_row = t >> 3;
  const int s_swz = (t & 7) ^ (s_row & 7);

  const unsigned short* kbase = k_ws + (size_t)bh * SEQ * 64;
  const unsigned short* vbase = vt_ws + (size_t)bh * 64 * SEQ;

  auto stage = [&](int kt, int kb, int vb) {
    gload16(kbase + (size_t)kt * 4096 + s_row * 64 + s_swz * 8, &Ks[kb][w * 512]);
    gload16(vbase + (size_t)s_row * SEQ + kt * 64 + s_swz * 8, &Vs[vb][w * 512]);
  };

  // Q fragments: lane holds Q[q = wq0+ql][d = 16*ks + 8*hi + j]
  const unsigned short* qr = q_ws + ((size_t)bh * SEQ + (wq0 + ql)) * 64;
  short8 qf[4];
#pragma unroll
  for (int ks = 0; ks < 4; ++ks)
    qf[ks] = *reinterpret_cast<const short8*>(qr + ks * 16 + hi * 8);

  f32x16 o0, o1;
#pragma unroll
  for (int i = 0; i < 16; ++i) { o0[i] = 0.f; o1[i] = 0.f; }
  float m_run = -1e30f, lsum = 0.f;
  short8 pa[4];   // P fragments of the PREVIOUS tile (T15 state)

  stage(0, 0, 0);

#pragma unroll 1
  for (int kt = 0; kt < nkt; ++kt) {
    __syncthreads();                       // tile kt's staged loads drained here
    if (kt + 1 < nkt) stage(kt + 1, (kt + 1) & 1, (kt + 1) % 3);
    const int cur = kt & 1;
    const int pvb = (kt + 2) % 3;          // == (kt-1) mod 3
    const int kt64 = kt * 64;
    const bool act  = (kt64 <= wq0 + 31);
    const bool actp = (kt > 0) && (kt64 - 64 <= wq0 + 31);

    f32x16 s0, s1;
    if (act) {
      // ---- QK^T (swapped: D[key][q], col=lane&31=q) ----
#pragma unroll
      for (int i = 0; i < 16; ++i) { s0[i] = 0.f; s1[i] = 0.f; }
      __builtin_amdgcn_s_setprio(1);
#pragma unroll
      for (int ks = 0; ks < 4; ++ks) {
        const short8 kfl = *reinterpret_cast<const short8*>(
            &Ks[cur][ql * 64 + (((2 * ks + hi) ^ (ql & 7)) << 3)]);
        const short8 kfh = *reinterpret_cast<const short8*>(
            &Ks[cur][(32 + ql) * 64 + (((2 * ks + hi) ^ (ql & 7)) << 3)]);
        s0 = __builtin_amdgcn_mfma_f32_32x32x16_bf16(kfl, qf[ks], s0, 0, 0, 0);
        s1 = __builtin_amdgcn_mfma_f32_32x32x16_bf16(kfh, qf[ks], s1, 0, 0, 0);
      }
      __builtin_amdgcn_s_setprio(0);
    }
    if (actp) {
      // ---- PV(t-1): overlaps softmax(t)'s VALU below (T15) ----
      __builtin_amdgcn_s_setprio(1);
#pragma unroll
      for (int ks = 0; ks < 4; ++ks) {
        const short8 vfl = *reinterpret_cast<const short8*>(
            &Vs[pvb][ql * 64 + (((2 * ks + hi) ^ (ql & 7)) << 3)]);
        const short8 vfh = *reinterpret_cast<const short8*>(
            &Vs[pvb][(32 + ql) * 64 + (((2 * ks + hi) ^ (ql & 7)) << 3)]);
        o0 = __builtin_amdgcn_mfma_f32_32x32x16_bf16(pa[ks], vfl, o0, 0, 0, 0);
        o1 = __builtin_amdgcn_mfma_f32_32x32x16_bf16(pa[ks], vfh, o1, 0, 0, 0);
      }
      __builtin_amdgcn_s_setprio(0);
    }
    if (act) {
      // ---- causal mask (diagonal straddle only) ----
      if (kt64 + 63 > wq0) {
        const int gq = wq0 + ql;
#pragma unroll
        for (int r = 0; r < 16; ++r) {
          const int krow = (r & 3) + 8 * (r >> 2) + 4 * hi;
          if (kt64 + krow > gq)      s0[r] = -1e30f;
          if (kt64 + 32 + krow > gq) s1[r] = -1e30f;
        }
      }
      // ---- online softmax (log2 domain), defer-max THR=10 ----
      float tm = -1e30f;
#pragma unroll
      for (int r = 0; r < 16; ++r) tm = fmaxf(tm, fmaxf(s0[r], s1[r]));
      tm = fmaxf(tm, __shfl_xor(tm, 32));
      if (__any(tm > m_run + 10.0f)) {
        const float m_new = fmaxf(m_run, tm);
        const float al = __builtin_amdgcn_exp2f(m_run - m_new);
        m_run = m_new;
        lsum *= al;
#pragma unroll
        for (int r = 0; r < 16; ++r) {
          const int qq = (r & 3) + 8 * (r >> 2) + 4 * hi;
          const float ar = __shfl(al, qq);
          o0[r] *= ar; o1[r] *= ar;
        }
      }
      float psum = 0.f;
      unsigned W[16];
#pragma unroll
      for (int half = 0; half < 2; ++half) {
#pragma unroll
        for (int gr = 0; gr < 4; ++gr) {
          const float v0 = (half ? s1[gr * 4 + 0] : s0[gr * 4 + 0]) - m_run;
          const float v1 = (half ? s1[gr * 4 + 1] : s0[gr * 4 + 1]) - m_run;
          const float v2 = (half ? s1[gr * 4 + 2] : s0[gr * 4 + 2]) - m_run;
          const float v3 = (half ? s1[gr * 4 + 3] : s0[gr * 4 + 3]) - m_run;
          const float p0 = __builtin_amdgcn_exp2f(v0);
          const float p1 = __builtin_amdgcn_exp2f(v1);
          const float p2 = __builtin_amdgcn_exp2f(v2);
          const float p3 = __builtin_amdgcn_exp2f(v3);
          psum += (p0 + p1) + (p2 + p3);
          W[half * 8 + 2 * gr]     = cvtpk_bf16(p0, p1);
          W[half * 8 + 2 * gr + 1] = cvtpk_bf16(p2, p3);
        }
      }
      lsum += psum;
      // redistribute P into PV A-operand fragments (register-only) -> pa (for next iter)
#pragma unroll
      for (int q4 = 0; q4 < 4; ++q4) {
        unsigned a0 = W[q4 * 4 + 0], a1 = W[q4 * 4 + 2];
        unsigned b0 = W[q4 * 4 + 1], b1 = W[q4 * 4 + 3];
        plswap(a0, a1);
        plswap(b0, b1);
        uint4v pk; pk[0] = a0; pk[1] = b0; pk[2] = a1; pk[3] = b1;
        pa[q4] = __builtin_bit_cast(short8, pk);
      }
    }
  }

  // ---- final PV for the last active tile ----
  if ((nkt - 1) * 64 <= wq0 + 31) {
    const int pvb = (nkt - 1) % 3;
    __builtin_amdgcn_s_setprio(1);
#pragma unroll
    for (int ks = 0; ks < 4; ++ks) {
      const short8 vfl = *reinterpret_cast<const short8*>(
          &Vs[pvb][ql * 64 + (((2 * ks + hi) ^ (ql & 7)) << 3)]);
      const short8 vfh = *reinterpret_cast<const short8*>(
          &Vs[pvb][(32 + ql) * 64 + (((2 * ks + hi) ^ (ql & 7)) << 3)]);
      o0 = __builtin_amdgcn_mfma_f32_32x32x16_bf16(pa[ks], vfl, o0, 0, 0, 0);
      o1 = __builtin_amdgcn_mfma_f32_32x32x16_bf16(pa[ks], vfh, o1, 0, 0, 0);
    }
    __builtin_amdgcn_s_setprio(0);
  }

  // ---- epilogue ----
  lsum += __shfl_xor(lsum, 32);
  const float linv = 1.f / lsum;
#pragma unroll
  for (int r = 0; r < 16; ++r) {
    const int qq = (r & 3) + 8 * (r >> 2) + 4 * hi;
    const float lr = __shfl(linv, qq);
    const size_t rowo = ((size_t)b * SEQ + (wq0 + qq)) * 1024 + h * 64;
    y_ws[rowo + ql]      = f2bf(o0[r] * lr);
    y_ws[rowo + 32 + ql] = f2bf(o1[r] * lr);
  }
}

extern "C" void kernel_launch(void* const* d_in, const int* in_sizes, int n_in,
                              void* d_out, int out_size, void* d_ws, size_t ws_size,
                              hipStream_t stream)
{
  (void)in_sizes; (void)n_in; (void)out_size; (void)ws_size;
  const float* x     = (const float*)d_in[0];
  const float* W_qkv = (const float*)d_in[1];
  const float* b_qkv = (const float*)d_in[2];
  const float* W_out = (const float*)d_in[3];
  const float* b_out = (const float*)d_in[4];
  float* out = (float*)d_out;

  unsigned short* ws      = (unsigned short*)d_ws;
  unsigned short* x_bf    = ws;
  unsigned short* wqkv_bf = x_bf    + (size_t)8192 * 1024;
  unsigned short* wout_bf = wqkv_bf + (size_t)3072 * 1024;
  unsigned short* q_ws    = wout_bf + (size_t)1024 * 1024;
  unsigned short* k_ws    = q_ws    + (size_t)64 * SEQ * 64;
  unsigned short* v_ws    = k_ws    + (size_t)64 * SEQ * 64;
  unsigned short* y_ws    = v_ws    + (size_t)64 * SEQ * 64;
  unsigned short* vt_ws   = x_bf;   // x_bf dead after qkv GEMM

  cvt_all<<<2048, 256, 0, stream>>>(x, W_qkv, W_out, x_bf);

  gemm_bt<0><<<dim3(24, 64), 256, 0, stream>>>(x_bf, wqkv_bf, b_qkv, q_ws, k_ws, v_ws, nullptr, 3072);
  transpose_v<<<dim3(SEQ / 64, 64), 256, 0, stream>>>(v_ws, vt_ws);
  attn_fwd6<<<dim3(8, 64), 512, 0, stream>>>(q_ws, k_ws, vt_ws, y_ws);
  gemm_bt<1><<<dim3(8, 64), 256, 0, stream>>>(y_ws, wout_bf, b_out, nullptr, nullptr, nullptr, out, 1024);
}